// Round 1
// baseline (265.412 us; speedup 1.0000x reference)
//
#include <hip/hip_runtime.h>
#include <hip/hip_bf16.h>
#include <stdint.h>

// MFMA fragment types per cdna_hip_programming.md §3 (gfx950-verified)
typedef __attribute__((ext_vector_type(8))) short bf16x8;  // 8 bf16 in 4 VGPRs
typedef __attribute__((ext_vector_type(4))) float f32x4;   // 4 f32 acc

#define RD 1024              // INPUT_DIM == REPR_DIM
#define LD 112               // N_LABELS
#define SCALE_C 2.8853900817779268f   // 2/ln(2): tanh(x) = 1 - 2/(1+2^(C*x))

// pack two floats' high-16 (truncated bf16) into one dword: lo=bf(lo), hi=bf(hi)
static __device__ __forceinline__ unsigned pkbf(float lo, float hi){
  return __builtin_amdgcn_perm(__builtin_bit_cast(unsigned, hi),
                               __builtin_bit_cast(unsigned, lo), 0x07060302u);
}
// sigma = 1/(1 + 2^t)
static __device__ __forceinline__ float sigm2(float t){
#if __has_builtin(__builtin_amdgcn_exp2f)
  float e = __builtin_amdgcn_exp2f(t);
#else
  float e = exp2f(t);
#endif
#if __has_builtin(__builtin_amdgcn_rcpf)
  return __builtin_amdgcn_rcpf(1.0f + e);
#else
  return 1.0f / (1.0f + e);
#endif
}
// round-to-nearest-even f32 -> bf16 bits (used only in prep, off hot path)
static __device__ __forceinline__ short f2bf_rn(float f){
  unsigned u = __builtin_bit_cast(unsigned, f);
  return (short)((u + 0x7fffu + ((u >> 16) & 1u)) >> 16);
}

// ---------------- prep: fp (bf16), Pt2 = -2*P^T (bf16), SB[l] = sum_r P[r,l] + bias ----
__global__ void fence_prep(const float* __restrict__ x, const float* __restrict__ P,
                           const float* __restrict__ ob, short* __restrict__ fpb,
                           short* __restrict__ Pt2, float* __restrict__ SB, int ntok){
  int id = blockIdx.x * 256 + threadIdx.x;
  int nfp = ntok * RD;
  if (id < nfp){
    int t = id >> 10, d = id & (RD - 1);
    float v = 0.0f;
    if (t < ntok - 1) v = (d < RD/2) ? x[t*RD + d] : -x[(t+1)*RD + d];
    fpb[id] = f2bf_rn(v);
  } else if (id < nfp + LD*RD){
    int p = id - nfp;
    int l = p >> 10, r = p & (RD - 1);
    Pt2[p] = f2bf_rn(-2.0f * P[r*LD + l]);   // Pt2[l][r]
  } else if (id < nfp + LD*RD + LD){
    int l = id - (nfp + LD*RD);
    float s = 0.0f;
    for (int r = 0; r < RD; ++r) s += P[r*LD + l];
    SB[l] = s + ob[l];
  }
}

// ---------------- k1: y = fp * W^T ; store yA' = C*y, yB' = C*(y+b) -------------------
// wave = one 16-row m-tile x 64 cols (4 n-tiles). A,B frags direct from global.
__global__ __launch_bounds__(256, 2)
void fence_y(const short* __restrict__ fpb, const float* __restrict__ W,
             const float* __restrict__ b, float* __restrict__ yA,
             float* __restrict__ yB, int mtiles, int ntok){
  int wid  = blockIdx.x * 4 + (threadIdx.x >> 6);
  int lane = threadIdx.x & 63;
  int mt = wid >> 4;
  int ng = wid & 15;
  if (mt >= mtiles) return;
  int lm = lane & 15, quad = lane >> 4;
  int arow = mt*16 + lm; if (arow > ntok - 1) arow = ntok - 1;
  const short* Ap = fpb + (size_t)arow*RD + quad*8;
  int rb = ng * 64;
  const float* Wp[4];
  #pragma unroll
  for (int nt = 0; nt < 4; ++nt) Wp[nt] = W + (size_t)(rb + nt*16 + lm)*RD + quad*8;

  f32x4 acc[4] = {};
  for (int kb = 0; kb < RD/32; ++kb){
    int ko = kb * 32;
    bf16x8 a = *(const bf16x8*)(Ap + ko);
    #pragma unroll
    for (int nt = 0; nt < 4; ++nt){
      float4 w0 = *(const float4*)(Wp[nt] + ko);
      float4 w1 = *(const float4*)(Wp[nt] + ko + 4);
      union { unsigned u4[4]; bf16x8 v; } wf;
      wf.u4[0] = pkbf(w0.x, w0.y); wf.u4[1] = pkbf(w0.z, w0.w);
      wf.u4[2] = pkbf(w1.x, w1.y); wf.u4[3] = pkbf(w1.z, w1.w);
      acc[nt] = __builtin_amdgcn_mfma_f32_16x16x32_bf16(a, wf.v, acc[nt], 0, 0, 0);
    }
  }
  // D layout: col = lane&15 (-> r), row = quad*4+reg (-> t)
  #pragma unroll
  for (int nt = 0; nt < 4; ++nt){
    int r = rb + nt*16 + lm;
    float bv = b[r];
    #pragma unroll
    for (int reg = 0; reg < 4; ++reg){
      int t = mt*16 + quad*4 + reg;
      if (t < ntok){
        float y = acc[nt][reg];
        yA[(size_t)t*RD + r] = SCALE_C * y;
        yB[(size_t)t*RD + r] = SCALE_C * (y + bv);
      }
    }
  }
}

// ---------------- k2: out[i,j,l] = SB[l] + sum_r sigma_ij[r] * (-2P[r,l]) --------------
// block = 16i x 16j pair tile; wave owns 4 i-rows (4 m-tiles) x 7 n-tiles. No LDS.
__global__ __launch_bounds__(256, 2)
void fence_out(const float* __restrict__ yA, const float* __restrict__ yB,
               const short* __restrict__ Pt2, const float* __restrict__ SB,
               float* __restrict__ out, int nn, int ntile){
  int wave = threadIdx.x >> 6;
  int lane = threadIdx.x & 63;
  int it = blockIdx.x / ntile;
  int jt = blockIdx.x - it*ntile;
  int lm = lane & 15, quad = lane >> 4;
  int ibase = it*16, jbase = jt*16;

  int jrow = jbase + lm; if (jrow > nn - 1) jrow = nn - 1;
  const float* yBp = yB + (size_t)jrow*RD + quad*8;
  const float* yAp[4];
  #pragma unroll
  for (int u = 0; u < 4; ++u){
    int ir = ibase + wave*4 + u; if (ir > nn - 1) ir = nn - 1;
    yAp[u] = yA + (size_t)ir*RD + quad*8;
  }
  const short* Pp = Pt2 + (size_t)lm*RD + quad*8;

  f32x4 acc[4][7];
  #pragma unroll
  for (int nt = 0; nt < 7; ++nt){
    float sv = SB[nt*16 + lm];
    #pragma unroll
    for (int u = 0; u < 4; ++u) acc[u][nt] = (f32x4){sv, sv, sv, sv};
  }

  for (int kb = 0; kb < RD/32; ++kb){
    int ko = kb * 32;
    float4 b0 = *(const float4*)(yBp + ko);
    float4 b1 = *(const float4*)(yBp + ko + 4);
    bf16x8 pf[7];
    #pragma unroll
    for (int nt = 0; nt < 7; ++nt) pf[nt] = *(const bf16x8*)(Pp + (size_t)nt*16*RD + ko);
    #pragma unroll
    for (int u = 0; u < 4; ++u){
      float4 a0 = *(const float4*)(yAp[u] + ko);
      float4 a1 = *(const float4*)(yAp[u] + ko + 4);
      float r0 = sigm2(b0.x - a0.x), r1 = sigm2(b0.y - a0.y);
      float r2 = sigm2(b0.z - a0.z), r3 = sigm2(b0.w - a0.w);
      float r4 = sigm2(b1.x - a1.x), r5 = sigm2(b1.y - a1.y);
      float r6 = sigm2(b1.z - a1.z), r7 = sigm2(b1.w - a1.w);
      union { unsigned u4[4]; bf16x8 v; } af;
      af.u4[0] = pkbf(r0, r1); af.u4[1] = pkbf(r2, r3);
      af.u4[2] = pkbf(r4, r5); af.u4[3] = pkbf(r6, r7);
      #pragma unroll
      for (int nt = 0; nt < 7; ++nt)
        acc[u][nt] = __builtin_amdgcn_mfma_f32_16x16x32_bf16(af.v, pf[nt], acc[u][nt], 0, 0, 0);
    }
  }

  // D layout: col = lane&15 (-> label), row = quad*4+reg (-> j within tile)
  #pragma unroll
  for (int u = 0; u < 4; ++u){
    int i = ibase + wave*4 + u;
    if (i >= nn) continue;
    size_t obase = (size_t)i * nn * LD;
    #pragma unroll
    for (int reg = 0; reg < 4; ++reg){
      int j = jbase + quad*4 + reg;
      if (j >= nn) continue;
      float* op = out + obase + (size_t)j*LD + lm;
      #pragma unroll
      for (int nt = 0; nt < 7; ++nt) op[nt*16] = acc[u][nt][reg];
    }
  }
}

extern "C" void kernel_launch(void* const* d_in, const int* in_sizes, int n_in,
                              void* d_out, int out_size, void* d_ws, size_t ws_size,
                              hipStream_t stream){
  const float* x  = (const float*)d_in[0];
  const float* W  = (const float*)d_in[1];
  const float* b  = (const float*)d_in[2];
  const float* P  = (const float*)d_in[3];
  const float* ob = (const float*)d_in[4];
  int ntok = in_sizes[0] / RD;   // 400
  int nn = ntok - 1;             // 399

  char* ws = (char*)d_ws;
  size_t szY = (size_t)ntok * RD * sizeof(float);      // 1.64 MB, rows padded to ntok
  float* yA  = (float*)ws;
  float* yB  = (float*)(ws + szY);
  short* fpb = (short*)(ws + 2*szY);
  short* Pt2 = (short*)(ws + 2*szY + (size_t)ntok*RD*2);
  float* SB  = (float*)(ws + 2*szY + (size_t)ntok*RD*2 + (size_t)LD*RD*2);

  int preptot = ntok*RD + LD*RD + LD;
  fence_prep<<<(preptot + 255)/256, 256, 0, stream>>>(x, P, ob, fpb, Pt2, SB, ntok);

  int mtiles = (nn + 15) / 16;   // 25
  fence_y<<<mtiles*4, 256, 0, stream>>>(fpb, W, b, yA, yB, mtiles, ntok);

  int ntile = (nn + 15) / 16;    // 25
  fence_out<<<ntile*ntile, 256, 0, stream>>>(yA, yB, Pt2, SB, (float*)d_out, nn, ntile);
}

// Round 2
// 206.339 us; speedup vs baseline: 1.2863x; 1.2863x over previous
//
#include <hip/hip_runtime.h>
#include <hip/hip_bf16.h>
#include <stdint.h>

typedef __attribute__((ext_vector_type(8))) short bf16x8;  // 8 bf16 (4 VGPRs)
typedef __attribute__((ext_vector_type(4))) float f32x4;   // 4 f32 acc

#define RD 1024
#define LD 112
#define SCALE_C 2.8853900817779268f   // 2/ln2: tanh(z) = 1 - 2/(1+2^(C*z))
#define CHK 64                        // k per LDS chunk in fence_out
#define NCHK (RD/CHK)                 // 16 chunks

// pack two floats' high-16 (trunc bf16) into one dword
static __device__ __forceinline__ unsigned pkbf(float lo, float hi){
  return __builtin_amdgcn_perm(__builtin_bit_cast(unsigned, hi),
                               __builtin_bit_cast(unsigned, lo), 0x07060302u);
}
static __device__ __forceinline__ float exp2_f(float t){
#if __has_builtin(__builtin_amdgcn_exp2f)
  return __builtin_amdgcn_exp2f(t);
#else
  return exp2f(t);
#endif
}
static __device__ __forceinline__ float rcp_f(float t){
#if __has_builtin(__builtin_amdgcn_rcpf)
  return __builtin_amdgcn_rcpf(t);
#else
  return 1.0f / t;
#endif
}
static __device__ __forceinline__ short f2bf_rn(float f){
  unsigned u = __builtin_bit_cast(unsigned, f);
  return (short)((u + 0x7fffu + ((u >> 16) & 1u)) >> 16);
}
// async global->LDS, 16B per lane; LDS dest = uniform base + lane*16
typedef const __attribute__((address_space(1))) unsigned int* gas1;
typedef __attribute__((address_space(3))) unsigned int* las3;
static __device__ __forceinline__ void g2lds16(const void* g, void* l){
  __builtin_amdgcn_global_load_lds((gas1)g, (las3)l, 16, 0, 0);
}

// ---- prep: fpb = bf16 fencepost feats; Wb = bf16 W; Pt2[l][r] = bf16(-2*P[r][l]) ----
__global__ void fence_prep(const float* __restrict__ x, const float* __restrict__ W,
                           const float* __restrict__ P, short* __restrict__ fpb,
                           short* __restrict__ Wb, short* __restrict__ Pt2, int ntok){
  int id = blockIdx.x * 256 + threadIdx.x;
  int nfp = ntok * RD;
  if (id < nfp){
    int t = id >> 10, d = id & (RD - 1);
    float v = 0.0f;
    if (t < ntok - 1) v = (d < RD/2) ? x[t*RD + d] : -x[(t+1)*RD + d];
    fpb[id] = f2bf_rn(v);
  } else if (id < nfp + RD*RD){
    int p = id - nfp;
    Wb[p] = f2bf_rn(W[p]);
  } else if (id < nfp + RD*RD + LD*RD){
    int p = id - nfp - RD*RD;
    int l = p >> 10, r = p & (RD - 1);
    Pt2[p] = f2bf_rn(-2.0f * P[r*LD + l]);
  }
}

// ---- SB[l] = sum_r P[r][l] + out_bias[l]  (112 blocks, parallel reduction) ----
__global__ void fence_sb(const float* __restrict__ P, const float* __restrict__ ob,
                         float* __restrict__ SB){
  __shared__ float red[256];
  int l = blockIdx.x, t = threadIdx.x;
  float s = 0.0f;
  for (int r = t; r < RD; r += 256) s += P[r*LD + l];
  red[t] = s; __syncthreads();
  for (int st = 128; st > 0; st >>= 1){
    if (t < st) red[t] += red[t + st];
    __syncthreads();
  }
  if (t == 0) SB[l] = red[0] + ob[l];
}

// ---- fence_y: y = fp*W^T (bf16 MFMA), fused epilogue E=2^(C(y+b)), F=2^(-Cy) ----
// 1 wave = 16 t-rows x 16 r-cols, grid mtiles*16 blocks of 4 waves (1600 waves)
__global__ __launch_bounds__(256, 4)
void fence_y(const short* __restrict__ fpb, const short* __restrict__ Wb,
             const float* __restrict__ b, float* __restrict__ E,
             float* __restrict__ F, int ntok){
  int wid  = blockIdx.x * 4 + (threadIdx.x >> 6);
  int lane = threadIdx.x & 63;
  int mt = wid >> 6;          // 0..24
  int ng = wid & 63;          // 0..63
  int lm = lane & 15, rq = lane >> 4;
  int arow = mt*16 + lm; if (arow > ntok - 1) arow = ntok - 1;
  const short* Ap = fpb + (size_t)arow*RD + rq*8;
  const short* Bp = Wb + (size_t)(ng*16 + lm)*RD + rq*8;
  f32x4 acc = {};
  #pragma unroll
  for (int kb = 0; kb < 32; ++kb){
    bf16x8 a = *(const bf16x8*)(Ap + kb*32);
    bf16x8 w = *(const bf16x8*)(Bp + kb*32);
    acc = __builtin_amdgcn_mfma_f32_16x16x32_bf16(a, w, acc, 0, 0, 0);
  }
  int r = ng*16 + lm;
  float bv = b[r];
  #pragma unroll
  for (int reg = 0; reg < 4; ++reg){
    int t = mt*16 + rq*4 + reg;
    if (t < ntok){
      float y = acc[reg];
      E[(size_t)t*RD + r] = exp2_f(SCALE_C * (y + bv));
      F[(size_t)t*RD + r] = exp2_f(-SCALE_C * y);
    }
  }
}

// ---- fence_out: out[i,j,l] = SB[l] + sum_r sigma * (-2P[r,l]),
//      sigma = 1/(1 + E[j,r]*F[i,r]).  Block = 12 i x 16 j, 4 waves x 3 i-rows.
//      Pt2 staged in LDS (64-k chunks, double-buffered, global_load_lds w=16).
__global__ __launch_bounds__(256, 3)
void fence_out(const float* __restrict__ E, const float* __restrict__ F,
               const short* __restrict__ Pt2, const float* __restrict__ SB,
               float* __restrict__ out, int nn, int njt){
  __shared__ short pbuf[2][14*512];   // 2 x 14 KB
  int wave = threadIdx.x >> 6, lane = threadIdx.x & 63;
  int lm = lane & 15, rq = lane >> 4;
  int it = blockIdx.x / njt, jt = blockIdx.x - it*njt;
  int ibase = it*12 + wave*3;
  int jbase = jt*16;
  int jrow = jbase + lm; if (jrow > nn - 1) jrow = nn - 1;
  const float* Ep = E + (size_t)jrow*RD + rq*8;
  const float* Fp[3];
  #pragma unroll
  for (int u = 0; u < 3; ++u){
    int ir = ibase + u; if (ir > nn - 1) ir = nn - 1;
    Fp[u] = F + (size_t)ir*RD + rq*8;
  }
  f32x4 acc[3][7];
  #pragma unroll
  for (int nt = 0; nt < 7; ++nt){
    float sv = SB[nt*16 + lm];
    #pragma unroll
    for (int u = 0; u < 3; ++u) acc[u][nt] = (f32x4){sv, sv, sv, sv};
  }

  // stage chunk c into buffer bi: 14 1KB-blocks (kb 0..1, g 0..6), waves round-robin
  auto stage = [&](int c, int bi){
    for (int bb = wave; bb < 14; bb += 4){
      int kb = bb / 7, g = bb - kb*7;
      const short* gp = Pt2 + (size_t)(g*16 + lm)*RD + c*CHK + kb*32 + rq*8;
      g2lds16(gp, &pbuf[bi][bb*512]);
    }
  };

  stage(0, 0);
  __syncthreads();
  for (int c = 0; c < NCHK; ++c){
    int bi = c & 1;
    if (c + 1 < NCHK) stage(c + 1, bi ^ 1);
    #pragma unroll
    for (int kb = 0; kb < 2; ++kb){
      int kk = c*CHK + kb*32;
      float4 e0 = *(const float4*)(Ep + kk);
      float4 e1 = *(const float4*)(Ep + kk + 4);
      bf16x8 af[3];
      #pragma unroll
      for (int u = 0; u < 3; ++u){
        float4 f0 = *(const float4*)(Fp[u] + kk);
        float4 f1 = *(const float4*)(Fp[u] + kk + 4);
        float s0 = rcp_f(fmaf(e0.x, f0.x, 1.0f));
        float s1 = rcp_f(fmaf(e0.y, f0.y, 1.0f));
        float s2 = rcp_f(fmaf(e0.z, f0.z, 1.0f));
        float s3 = rcp_f(fmaf(e0.w, f0.w, 1.0f));
        float s4 = rcp_f(fmaf(e1.x, f1.x, 1.0f));
        float s5 = rcp_f(fmaf(e1.y, f1.y, 1.0f));
        float s6 = rcp_f(fmaf(e1.z, f1.z, 1.0f));
        float s7 = rcp_f(fmaf(e1.w, f1.w, 1.0f));
        union { unsigned u4[4]; bf16x8 v; } a;
        a.u4[0] = pkbf(s0, s1); a.u4[1] = pkbf(s2, s3);
        a.u4[2] = pkbf(s4, s5); a.u4[3] = pkbf(s6, s7);
        af[u] = a.v;
      }
      #pragma unroll
      for (int nt = 0; nt < 7; ++nt){
        bf16x8 pf = *(const bf16x8*)&pbuf[bi][(kb*7 + nt)*512 + rq*128 + lm*8];
        #pragma unroll
        for (int u = 0; u < 3; ++u)
          acc[u][nt] = __builtin_amdgcn_mfma_f32_16x16x32_bf16(af[u], pf, acc[u][nt], 0, 0, 0);
      }
    }
    __syncthreads();
  }

  // D layout: col=lm -> label, row=rq*4+reg -> j
  #pragma unroll
  for (int u = 0; u < 3; ++u){
    int i = ibase + u;
    if (i >= nn) continue;
    size_t obase = (size_t)i * nn * LD;
    #pragma unroll
    for (int reg = 0; reg < 4; ++reg){
      int j = jbase + rq*4 + reg;
      if (j >= nn) continue;
      float* op = out + obase + (size_t)j*LD + lm;
      #pragma unroll
      for (int nt = 0; nt < 7; ++nt) op[nt*16] = acc[u][nt][reg];
    }
  }
}

extern "C" void kernel_launch(void* const* d_in, const int* in_sizes, int n_in,
                              void* d_out, int out_size, void* d_ws, size_t ws_size,
                              hipStream_t stream){
  const float* x  = (const float*)d_in[0];
  const float* W  = (const float*)d_in[1];
  const float* b  = (const float*)d_in[2];
  const float* P  = (const float*)d_in[3];
  const float* ob = (const float*)d_in[4];
  int ntok = in_sizes[0] / RD;   // 400
  int nn = ntok - 1;             // 399

  char* ws = (char*)d_ws;
  size_t o_fpb = 0;
  size_t o_Wb  = o_fpb + (size_t)ntok*RD*2;          // 819200
  size_t o_Pt2 = o_Wb  + (size_t)RD*RD*2;            // +2 MB
  size_t o_E   = o_Pt2 + (size_t)LD*RD*2;            // +224 KB
  size_t o_F   = o_E   + (size_t)ntok*RD*4;          // +1.6 MB
  size_t o_SB  = o_F   + (size_t)ntok*RD*4;          // +1.6 MB
  short* fpb = (short*)(ws + o_fpb);
  short* Wb  = (short*)(ws + o_Wb);
  short* Pt2 = (short*)(ws + o_Pt2);
  float* E   = (float*)(ws + o_E);
  float* F   = (float*)(ws + o_F);
  float* SB  = (float*)(ws + o_SB);

  int preptot = ntok*RD + RD*RD + LD*RD;
  fence_prep<<<(preptot + 255)/256, 256, 0, stream>>>(x, W, P, fpb, Wb, Pt2, ntok);
  fence_sb<<<LD, 256, 0, stream>>>(P, ob, SB);

  int mtiles = (ntok + 15) / 16;   // 25
  fence_y<<<mtiles*16, 256, 0, stream>>>(fpb, Wb, b, E, F, ntok);

  int njt = (nn + 15) / 16;        // 25
  int nit = (nn + 11) / 12;        // 34
  fence_out<<<nit*njt, 256, 0, stream>>>(E, F, Pt2, SB, (float*)d_out, nn, njt);
}

// Round 4
// 165.328 us; speedup vs baseline: 1.6054x; 1.2481x over previous
//
#include <hip/hip_runtime.h>
#include <hip/hip_bf16.h>
#include <stdint.h>

typedef __attribute__((ext_vector_type(8))) short bf16x8;  // 8 bf16 (4 VGPRs)
typedef __attribute__((ext_vector_type(4))) float f32x4;   // 4 f32 acc

#define RD 1024
#define LD 112
#define SCALE_C 2.8853900817779268f   // 2/ln2: tanh(z) = 1 - 2/(1+2^(C*z))
#define CHK 64                        // k per LDS chunk in fence_out
#define NCHK (RD/CHK)                 // 16 chunks
#define NB_CONV 6144                  // (400*1024 + 1024*1024 + 112*1024)/256

static __device__ __forceinline__ unsigned pkbf(float lo, float hi){
  return __builtin_amdgcn_perm(__builtin_bit_cast(unsigned, hi),
                               __builtin_bit_cast(unsigned, lo), 0x07060302u);
}
static __device__ __forceinline__ float exp2_f(float t){
#if __has_builtin(__builtin_amdgcn_exp2f)
  return __builtin_amdgcn_exp2f(t);
#else
  return exp2f(t);
#endif
}
static __device__ __forceinline__ float rcp_f(float t){
#if __has_builtin(__builtin_amdgcn_rcpf)
  return __builtin_amdgcn_rcpf(t);
#else
  return 1.0f / t;
#endif
}
static __device__ __forceinline__ short f2bf_rn(float f){
  unsigned u = __builtin_bit_cast(unsigned, f);
  return (short)((u + 0x7fffu + ((u >> 16) & 1u)) >> 16);
}
typedef const __attribute__((address_space(1))) unsigned int* gas1;
typedef __attribute__((address_space(3))) unsigned int* las3;
static __device__ __forceinline__ void g2lds16(const void* g, void* l){
  __builtin_amdgcn_global_load_lds((gas1)g, (las3)l, 16, 0, 0);
}

// ---- fused prep: bf16 conversions + SB[l] = sum_r P[r][l] + out_bias[l] ----
__global__ void fence_prep(const float* __restrict__ x, const float* __restrict__ W,
                           const float* __restrict__ P, const float* __restrict__ ob,
                           short* __restrict__ fpb, short* __restrict__ Wb,
                           short* __restrict__ Pt2, float* __restrict__ SB, int ntok){
  __shared__ float red[256];
  int blk = blockIdx.x, t = threadIdx.x;
  if (blk < NB_CONV){
    int id = blk*256 + t;
    int nfp = ntok * RD;
    if (id < nfp){
      int tok = id >> 10, d = id & (RD - 1);
      float v = 0.0f;
      if (tok < ntok - 1) v = (d < RD/2) ? x[tok*RD + d] : -x[(tok+1)*RD + d];
      fpb[id] = f2bf_rn(v);
    } else if (id < nfp + RD*RD){
      int p = id - nfp;
      Wb[p] = f2bf_rn(W[p]);
    } else {
      int p = id - nfp - RD*RD;   // < LD*RD by exact grid sizing
      int l = p >> 10, r = p & (RD - 1);
      Pt2[p] = f2bf_rn(-2.0f * P[r*LD + l]);
    }
  } else {
    int l = blk - NB_CONV;        // 0..LD-1
    float s = 0.0f;
    for (int r = t; r < RD; r += 256) s += P[r*LD + l];
    red[t] = s; __syncthreads();
    for (int st = 128; st > 0; st >>= 1){
      if (t < st) red[t] += red[t + st];
      __syncthreads();
    }
    if (t == 0) SB[l] = red[0] + ob[l];
  }
}

// ---- fence_y: y = fp*W^T (bf16 MFMA); epilogue E=2^(C(y+b)), F=2^(-Cy) ----
// 1 wave = 16 t-rows x 16 r-cols; 400 blocks x 4 waves = 1600 tiles. (R2-proven)
__global__ __launch_bounds__(256, 4)
void fence_y(const short* __restrict__ fpb, const short* __restrict__ Wb,
             const float* __restrict__ b, float* __restrict__ E,
             float* __restrict__ F, int ntok){
  int wid  = blockIdx.x * 4 + (threadIdx.x >> 6);
  int lane = threadIdx.x & 63;
  int mt = wid >> 6;          // 0..24
  int ng = wid & 63;          // 0..63
  int lm = lane & 15, rq = lane >> 4;
  int arow = mt*16 + lm; if (arow > ntok - 1) arow = ntok - 1;
  const short* Ap = fpb + (size_t)arow*RD + rq*8;
  const short* Bp = Wb + (size_t)(ng*16 + lm)*RD + rq*8;
  f32x4 acc = {};
  #pragma unroll
  for (int kb = 0; kb < 32; ++kb){
    bf16x8 a = *(const bf16x8*)(Ap + kb*32);
    bf16x8 w = *(const bf16x8*)(Bp + kb*32);
    acc = __builtin_amdgcn_mfma_f32_16x16x32_bf16(a, w, acc, 0, 0, 0);
  }
  int r = ng*16 + lm;
  float bv = b[r];
  #pragma unroll
  for (int reg = 0; reg < 4; ++reg){
    int t = mt*16 + rq*4 + reg;
    if (t < ntok){
      float y = acc[reg];
      E[(size_t)t*RD + r] = exp2_f(SCALE_C * (y + bv));
      F[(size_t)t*RD + r] = exp2_f(-SCALE_C * y);
    }
  }
}

// ---- fence_out: out[i,j,l] = SB[l] - 2*sum_r sigma*P[r,l], sigma=1/(1+E_j F_i).
//      Block = 8i x 16j, 4 waves x 2 i-rows. Pt2 AND E AND F all staged into
//      LDS per 64-k chunk via global_load_lds (double-buffered, 40 KB total ->
//      4 blocks/CU). Hot chain is ds_read -> sigma -> MFMA only. ----
__global__ __launch_bounds__(256, 4)
void fence_out(const float* __restrict__ E, const float* __restrict__ F,
               const short* __restrict__ Pt2, const float* __restrict__ SB,
               float* __restrict__ out, int nn, int njt){
  __shared__ short pbuf[2][14*512];   // Pt2 chunk: 112 labels x 64 k bf16 = 14 KB
  __shared__ float ebuf[2][16*64];    // E chunk: 16 j-rows x 64 f32 = 4 KB
  __shared__ float fbuf[2][8*64];     // F chunk:  8 i-rows x 64 f32 = 2 KB
  int wave = threadIdx.x >> 6, lane = threadIdx.x & 63;
  int lm = lane & 15, rq = lane >> 4;
  int it = blockIdx.x / njt, jt = blockIdx.x - it*njt;
  int ibase = it*8, jbase = jt*16;

  f32x4 acc[2][7];
  #pragma unroll
  for (int nt = 0; nt < 7; ++nt){
    float sv = SB[nt*16 + lm];
    acc[0][nt] = (f32x4){sv, sv, sv, sv};
    acc[1][nt] = (f32x4){sv, sv, sv, sv};
  }

  // 20 stage calls per chunk (14 Pt2 + 4 E + 2 F), round-robin over 4 waves.
  auto stage = [&](int c, int bi){
    for (int q = wave; q < 20; q += 4){
      if (q < 14){
        int kb = q / 7, g = q - kb*7;
        const short* gp = Pt2 + (size_t)(g*16 + lm)*RD + c*CHK + kb*32 + rq*8;
        g2lds16(gp, &pbuf[bi][q*512]);
      } else if (q < 18){
        int ee = q - 14;
        int row = ee*4 + rq;                    // 0..15
        int jr = jbase + row; if (jr > nn - 1) jr = nn - 1;
        const float* gp = E + (size_t)jr*RD + c*CHK + lm*4;
        g2lds16(gp, &ebuf[bi][ee*256]);
      } else {
        int ff = q - 18;
        int row = ff*4 + rq;                    // 0..7
        int ir = ibase + row; if (ir > nn - 1) ir = nn - 1;
        const float* gp = F + (size_t)ir*RD + c*CHK + lm*4;
        g2lds16(gp, &fbuf[bi][ff*256]);
      }
    }
  };

  stage(0, 0);
  __syncthreads();
  for (int c = 0; c < NCHK; ++c){
    int bi = c & 1;
    if (c + 1 < NCHK) stage(c + 1, bi ^ 1);
    #pragma unroll
    for (int kb = 0; kb < 2; ++kb){
      int ko = kb*32 + rq*8;
      // E row = this lane's j (lm); F row = wave's i-row (uniform, broadcast)
      float4 e0 = *(const float4*)&ebuf[bi][lm*64 + ko];
      float4 e1 = *(const float4*)&ebuf[bi][lm*64 + ko + 4];
      bf16x8 af[2];
      #pragma unroll
      for (int u = 0; u < 2; ++u){
        const float* fr = &fbuf[bi][(wave*2 + u)*64 + ko];
        float4 f0 = *(const float4*)fr;
        float4 f1 = *(const float4*)(fr + 4);
        float s0 = rcp_f(fmaf(e0.x, f0.x, 1.0f));
        float s1 = rcp_f(fmaf(e0.y, f0.y, 1.0f));
        float s2 = rcp_f(fmaf(e0.z, f0.z, 1.0f));
        float s3 = rcp_f(fmaf(e0.w, f0.w, 1.0f));
        float s4 = rcp_f(fmaf(e1.x, f1.x, 1.0f));
        float s5 = rcp_f(fmaf(e1.y, f1.y, 1.0f));
        float s6 = rcp_f(fmaf(e1.z, f1.z, 1.0f));
        float s7 = rcp_f(fmaf(e1.w, f1.w, 1.0f));
        union { unsigned u4[4]; bf16x8 v; } a;
        a.u4[0] = pkbf(s0, s1); a.u4[1] = pkbf(s2, s3);
        a.u4[2] = pkbf(s4, s5); a.u4[3] = pkbf(s6, s7);
        af[u] = a.v;
      }
      #pragma unroll
      for (int nt = 0; nt < 7; ++nt){
        bf16x8 pf = *(const bf16x8*)&pbuf[bi][(kb*7 + nt)*512 + lane*8];
        acc[0][nt] = __builtin_amdgcn_mfma_f32_16x16x32_bf16(af[0], pf, acc[0][nt], 0, 0, 0);
        acc[1][nt] = __builtin_amdgcn_mfma_f32_16x16x32_bf16(af[1], pf, acc[1][nt], 0, 0, 0);
      }
    }
    __syncthreads();
  }

  // D layout: col=lm -> label, row=rq*4+reg -> j
  #pragma unroll
  for (int u = 0; u < 2; ++u){
    int i = ibase + wave*2 + u;
    if (i >= nn) continue;
    size_t dbase = (size_t)i * nn * LD;
    #pragma unroll
    for (int reg = 0; reg < 4; ++reg){
      int j = jbase + rq*4 + reg;
      if (j >= nn) continue;
      float* op = out + dbase + (size_t)j*LD + lm;
      #pragma unroll
      for (int nt = 0; nt < 7; ++nt) op[nt*16] = acc[u][nt][reg];
    }
  }
}

extern "C" void kernel_launch(void* const* d_in, const int* in_sizes, int n_in,
                              void* d_out, int out_size, void* d_ws, size_t ws_size,
                              hipStream_t stream){
  const float* x  = (const float*)d_in[0];
  const float* W  = (const float*)d_in[1];
  const float* b  = (const float*)d_in[2];
  const float* P  = (const float*)d_in[3];
  const float* ob = (const float*)d_in[4];
  int ntok = in_sizes[0] / RD;   // 400
  int nn = ntok - 1;             // 399

  char* ws = (char*)d_ws;
  size_t o_fpb = 0;
  size_t o_Wb  = o_fpb + (size_t)ntok*RD*2;
  size_t o_Pt2 = o_Wb  + (size_t)RD*RD*2;
  size_t o_E   = o_Pt2 + (size_t)LD*RD*2;
  size_t o_F   = o_E   + (size_t)ntok*RD*4;
  size_t o_SB  = o_F   + (size_t)ntok*RD*4;
  short* fpb = (short*)(ws + o_fpb);
  short* Wb  = (short*)(ws + o_Wb);
  short* Pt2 = (short*)(ws + o_Pt2);
  float* E   = (float*)(ws + o_E);
  float* F   = (float*)(ws + o_F);
  float* SB  = (float*)(ws + o_SB);

  fence_prep<<<NB_CONV + LD, 256, 0, stream>>>(x, W, P, ob, fpb, Wb, Pt2, SB, ntok);

  int mtiles = (ntok + 15) / 16;       // 25
  fence_y<<<mtiles*16, 256, 0, stream>>>(fpb, Wb, b, E, F, ntok);

  int njt = (nn + 15) / 16;            // 25
  int nit = (nn + 7) / 8;              // 50
  fence_out<<<nit*njt, 256, 0, stream>>>(E, F, Pt2, SB, (float*)d_out, nn, njt);
}

// Round 5
// 161.892 us; speedup vs baseline: 1.6394x; 1.0212x over previous
//
#include <hip/hip_runtime.h>
#include <hip/hip_bf16.h>
#include <stdint.h>

typedef __attribute__((ext_vector_type(8))) short bf16x8;  // 8 bf16 (4 VGPRs)
typedef __attribute__((ext_vector_type(4))) float f32x4;   // 4 f32 acc

#define RD 1024
#define LD 112
#define SCALE_C 2.8853900817779268f   // 2/ln2: tanh(z) = 1 - 2/(1+2^(C*z))
#define CHK 64                        // k per LDS chunk in fence_out
#define NCHK (RD/CHK)                 // 16 chunks
#define NB_CONV 6144                  // (400*1024 + 1024*1024 + 112*1024)/256
// flat LDS chunk buffer layout (bytes): Pt2 14 KB | E 4 KB | F 2 KB = 20 KB
#define OFF_E 14336
#define OFF_F 18432

static __device__ __forceinline__ unsigned pkbf(float lo, float hi){
  return __builtin_amdgcn_perm(__builtin_bit_cast(unsigned, hi),
                               __builtin_bit_cast(unsigned, lo), 0x07060302u);
}
static __device__ __forceinline__ float exp2_f(float t){
#if __has_builtin(__builtin_amdgcn_exp2f)
  return __builtin_amdgcn_exp2f(t);
#else
  return exp2f(t);
#endif
}
static __device__ __forceinline__ float rcp_f(float t){
#if __has_builtin(__builtin_amdgcn_rcpf)
  return __builtin_amdgcn_rcpf(t);
#else
  return 1.0f / t;
#endif
}
static __device__ __forceinline__ short f2bf_rn(float f){
  unsigned u = __builtin_bit_cast(unsigned, f);
  return (short)((u + 0x7fffu + ((u >> 16) & 1u)) >> 16);
}
typedef const __attribute__((address_space(1))) unsigned int* gas1;
typedef __attribute__((address_space(3))) unsigned int* las3;
static __device__ __forceinline__ void g2lds16(const void* g, void* l){
  __builtin_amdgcn_global_load_lds((gas1)g, (las3)l, 16, 0, 0);
}

// ---- fused prep: bf16 conversions + SB[l] = sum_r P[r][l] + out_bias[l] ----
__global__ void fence_prep(const float* __restrict__ x, const float* __restrict__ W,
                           const float* __restrict__ P, const float* __restrict__ ob,
                           short* __restrict__ fpb, short* __restrict__ Wb,
                           short* __restrict__ Pt2, float* __restrict__ SB, int ntok){
  __shared__ float red[256];
  int blk = blockIdx.x, t = threadIdx.x;
  if (blk < NB_CONV){
    int id = blk*256 + t;
    int nfp = ntok * RD;
    if (id < nfp){
      int tok = id >> 10, d = id & (RD - 1);
      float v = 0.0f;
      if (tok < ntok - 1) v = (d < RD/2) ? x[tok*RD + d] : -x[(tok+1)*RD + d];
      fpb[id] = f2bf_rn(v);
    } else if (id < nfp + RD*RD){
      int p = id - nfp;
      Wb[p] = f2bf_rn(W[p]);
    } else {
      int p = id - nfp - RD*RD;   // < LD*RD by exact grid sizing
      int l = p >> 10, r = p & (RD - 1);
      Pt2[p] = f2bf_rn(-2.0f * P[r*LD + l]);
    }
  } else {
    int l = blk - NB_CONV;        // 0..LD-1
    float s = 0.0f;
    for (int r = t; r < RD; r += 256) s += P[r*LD + l];
    red[t] = s; __syncthreads();
    for (int st = 128; st > 0; st >>= 1){
      if (t < st) red[t] += red[t + st];
      __syncthreads();
    }
    if (t == 0) SB[l] = red[0] + ob[l];
  }
}

// ---- fence_y: y = fp*W^T (bf16 MFMA); epilogue E=2^(C(y+b)), F=2^(-Cy) ----
__global__ __launch_bounds__(256, 4)
void fence_y(const short* __restrict__ fpb, const short* __restrict__ Wb,
             const float* __restrict__ b, float* __restrict__ E,
             float* __restrict__ F, int ntok){
  int wid  = blockIdx.x * 4 + (threadIdx.x >> 6);
  int lane = threadIdx.x & 63;
  int mt = wid >> 6;          // 0..24
  int ng = wid & 63;          // 0..63
  int lm = lane & 15, rq = lane >> 4;
  int arow = mt*16 + lm; if (arow > ntok - 1) arow = ntok - 1;
  const short* Ap = fpb + (size_t)arow*RD + rq*8;
  const short* Bp = Wb + (size_t)(ng*16 + lm)*RD + rq*8;
  f32x4 acc = {};
  #pragma unroll
  for (int kb = 0; kb < 32; ++kb){
    bf16x8 a = *(const bf16x8*)(Ap + kb*32);
    bf16x8 w = *(const bf16x8*)(Bp + kb*32);
    acc = __builtin_amdgcn_mfma_f32_16x16x32_bf16(a, w, acc, 0, 0, 0);
  }
  int r = ng*16 + lm;
  float bv = b[r];
  #pragma unroll
  for (int reg = 0; reg < 4; ++reg){
    int t = mt*16 + rq*4 + reg;
    if (t < ntok){
      float y = acc[reg];
      E[(size_t)t*RD + r] = exp2_f(SCALE_C * (y + bv));
      F[(size_t)t*RD + r] = exp2_f(-SCALE_C * y);
    }
  }
}

// ---- fence_out: out[i,j,l] = SB[l] - 2*sum_r sigma*P[r,l], sigma=1/(1+E_j F_i).
//      Block = 8i x 16j, 4 waves x 2 i-rows. Pt2/E/F staged per 64-k chunk via
//      global_load_lds (double-buffered 2x20 KB). E chunk stored XOR-swizzled at
//      float4 granularity (slot s of row r holds global float4 s^r) so the
//      16-row-stride reads are bank-conflict-free without padding. ----
__global__ __launch_bounds__(256, 4)
void fence_out(const float* __restrict__ E, const float* __restrict__ F,
               const short* __restrict__ Pt2, const float* __restrict__ SB,
               float* __restrict__ out, int nn, int njt){
  __shared__ __align__(16) char sbuf[2][20480];
  int wave = threadIdx.x >> 6, lane = threadIdx.x & 63;
  int lm = lane & 15, rq = lane >> 4;
  int it = blockIdx.x / njt, jt = blockIdx.x - it*njt;
  int ibase = it*8, jbase = jt*16;

  // per-wave stage descriptors: 5 x 1KB blocks each (20 total), precomputed
  const char* gp[5]; int lof[5]; int stp[5];
  #pragma unroll
  for (int s = 0; s < 5; ++s){
    int q = wave + s*4;
    if (q < 14){                       // Pt2: 14 blocks of (7 labels-of-16 x 2 kb)
      int kb = q / 7, g = q - kb*7;
      gp[s]  = (const char*)(Pt2 + (size_t)(g*16 + lm)*RD + kb*32 + rq*8);
      stp[s] = CHK*2;
      lof[s] = q*1024;
    } else if (q < 18){                // E: 4 blocks of 4 j-rows, XOR-swizzled src
      int ee = q - 14;
      int row = ee*4 + rq;             // 0..15
      int jr = jbase + row; if (jr > nn - 1) jr = nn - 1;
      int cb = lm ^ row;               // swizzle: slot lm holds float4 (lm^row)
      gp[s]  = (const char*)(E + (size_t)jr*RD + cb*4);
      stp[s] = CHK*4;
      lof[s] = OFF_E + ee*1024;
    } else {                           // F: 2 blocks of 4 i-rows, linear
      int ff = q - 18;
      int row = ff*4 + rq;             // 0..7
      int ir = ibase + row; if (ir > nn - 1) ir = nn - 1;
      gp[s]  = (const char*)(F + (size_t)ir*RD + lm*4);
      stp[s] = CHK*4;
      lof[s] = OFF_F + ff*1024;
    }
  }
  auto stage = [&](int c, int bi){
    #pragma unroll
    for (int s = 0; s < 5; ++s)
      g2lds16(gp[s] + (size_t)c*stp[s], &sbuf[bi][lof[s]]);
  };

  stage(0, 0);

  f32x4 acc[2][7];
  #pragma unroll
  for (int nt = 0; nt < 7; ++nt){
    float sv = SB[nt*16 + lm];
    acc[0][nt] = (f32x4){sv, sv, sv, sv};
    acc[1][nt] = (f32x4){sv, sv, sv, sv};
  }
  __syncthreads();

  for (int c = 0; c < NCHK; ++c){
    int bi = c & 1;
    if (c + 1 < NCHK) stage(c + 1, bi ^ 1);
    const short* pb = (const short*)&sbuf[bi][0];
    const float* eb = (const float*)&sbuf[bi][OFF_E];
    const float* fb = (const float*)&sbuf[bi][OFF_F];
    #pragma unroll
    for (int kb = 0; kb < 2; ++kb){
      int ko = kb*32 + rq*8;
      int cb0 = kb*8 + rq*2;
      float4 e0 = *(const float4*)(eb + lm*64 + ((cb0 ^ lm) * 4));
      float4 e1 = *(const float4*)(eb + lm*64 + (((cb0 + 1) ^ lm) * 4));
      bf16x8 af[2];
      #pragma unroll
      for (int u = 0; u < 2; ++u){
        const float* fr = fb + (wave*2 + u)*64 + ko;   // wave-uniform: broadcast
        float4 f0 = *(const float4*)fr;
        float4 f1 = *(const float4*)(fr + 4);
        float s0 = rcp_f(fmaf(e0.x, f0.x, 1.0f));
        float s1 = rcp_f(fmaf(e0.y, f0.y, 1.0f));
        float s2 = rcp_f(fmaf(e0.z, f0.z, 1.0f));
        float s3 = rcp_f(fmaf(e0.w, f0.w, 1.0f));
        float s4 = rcp_f(fmaf(e1.x, f1.x, 1.0f));
        float s5 = rcp_f(fmaf(e1.y, f1.y, 1.0f));
        float s6 = rcp_f(fmaf(e1.z, f1.z, 1.0f));
        float s7 = rcp_f(fmaf(e1.w, f1.w, 1.0f));
        union { unsigned u4[4]; bf16x8 v; } a;
        a.u4[0] = pkbf(s0, s1); a.u4[1] = pkbf(s2, s3);
        a.u4[2] = pkbf(s4, s5); a.u4[3] = pkbf(s6, s7);
        af[u] = a.v;
      }
      #pragma unroll
      for (int nt = 0; nt < 7; ++nt){
        bf16x8 pf = *(const bf16x8*)(pb + (kb*7 + nt)*512 + lane*8);
        acc[0][nt] = __builtin_amdgcn_mfma_f32_16x16x32_bf16(af[0], pf, acc[0][nt], 0, 0, 0);
        acc[1][nt] = __builtin_amdgcn_mfma_f32_16x16x32_bf16(af[1], pf, acc[1][nt], 0, 0, 0);
      }
    }
    __syncthreads();
  }

  // D layout: col=lm -> label, row=rq*4+reg -> j
  #pragma unroll
  for (int u = 0; u < 2; ++u){
    int i = ibase + wave*2 + u;
    if (i >= nn) continue;
    size_t dbase = (size_t)i * nn * LD;
    #pragma unroll
    for (int reg = 0; reg < 4; ++reg){
      int j = jbase + rq*4 + reg;
      if (j >= nn) continue;
      float* op = out + dbase + (size_t)j*LD + lm;
      #pragma unroll
      for (int nt = 0; nt < 7; ++nt) op[nt*16] = acc[u][nt][reg];
    }
  }
}

extern "C" void kernel_launch(void* const* d_in, const int* in_sizes, int n_in,
                              void* d_out, int out_size, void* d_ws, size_t ws_size,
                              hipStream_t stream){
  const float* x  = (const float*)d_in[0];
  const float* W  = (const float*)d_in[1];
  const float* b  = (const float*)d_in[2];
  const float* P  = (const float*)d_in[3];
  const float* ob = (const float*)d_in[4];
  int ntok = in_sizes[0] / RD;   // 400
  int nn = ntok - 1;             // 399

  char* ws = (char*)d_ws;
  size_t o_fpb = 0;
  size_t o_Wb  = o_fpb + (size_t)ntok*RD*2;
  size_t o_Pt2 = o_Wb  + (size_t)RD*RD*2;
  size_t o_E   = o_Pt2 + (size_t)LD*RD*2;
  size_t o_F   = o_E   + (size_t)ntok*RD*4;
  size_t o_SB  = o_F   + (size_t)ntok*RD*4;
  short* fpb = (short*)(ws + o_fpb);
  short* Wb  = (short*)(ws + o_Wb);
  short* Pt2 = (short*)(ws + o_Pt2);
  float* E   = (float*)(ws + o_E);
  float* F   = (float*)(ws + o_F);
  float* SB  = (float*)(ws + o_SB);

  fence_prep<<<NB_CONV + LD, 256, 0, stream>>>(x, W, P, ob, fpb, Wb, Pt2, SB, ntok);

  int mtiles = (ntok + 15) / 16;       // 25
  fence_y<<<mtiles*16, 256, 0, stream>>>(fpb, Wb, b, E, F, ntok);

  int njt = (nn + 15) / 16;            // 25
  int nit = (nn + 7) / 8;              // 50
  fence_out<<<nit*njt, 256, 0, stream>>>(E, F, Pt2, SB, (float*)d_out, nn, njt);
}